// Round 1
// baseline (202.859 us; speedup 1.0000x reference)
//
#include <hip/hip_runtime.h>

// QSP: u = Rz(phi0) * prod_{k=1..127} [ Wx(theta) * Rz(phi_k) ]
// All factors are SU(2): u = [[a, b], [-conj(b), conj(a)]].
// Recurrence per step k:
//   t_a = a*c + i*b*s          (c = cos theta, s = sin theta)
//   t_b = i*a*s + b*c
//   a   = t_a * e_k            (e_k = exp(i*phi_k))
//   b   = t_b * conj(e_k)
// Output: real(a), imag(a) concatenated.

#define NPHI 128

__global__ __launch_bounds__(256) void qsp_kernel(
    const float* __restrict__ th,
    const float* __restrict__ phis,
    float* __restrict__ out,   // [0,B): real, [B,2B): imag
    int B)
{
    __shared__ float2 e[NPHI];  // (cos phi_k, sin phi_k)
    const int tid = threadIdx.x;
    if (tid < NPHI) {
        float p = phis[tid];
        float sp, cp;
        __sincosf(p, &sp, &cp);
        e[tid] = make_float2(cp, sp);
    }
    __syncthreads();

    const int i = blockIdx.x * blockDim.x + tid;
    if (i >= B) return;

    const float theta = th[i];
    float s, c;
    __sincosf(theta, &s, &c);

    // u0 = Rz(phi0): a = e0, b = 0
    float ar = e[0].x, ai = e[0].y;
    float br = 0.f, bi = 0.f;

    #pragma unroll 8
    for (int k = 1; k < NPHI; ++k) {
        const float2 ek = e[k];
        // t_a = a*c + i*b*s ; t_b = i*a*s + b*c
        const float tar = ar * c - bi * s;
        const float tai = ai * c + br * s;
        const float tbr = br * c - ai * s;
        const float tbi = bi * c + ar * s;
        // a = t_a * e_k
        ar = tar * ek.x - tai * ek.y;
        ai = tar * ek.y + tai * ek.x;
        // b = t_b * conj(e_k)
        br = tbr * ek.x + tbi * ek.y;
        bi = tbi * ek.x - tbr * ek.y;
    }

    out[i]     = ar;  // real(u[0,0])
    out[i + B] = ai;  // imag(u[0,0])
}

extern "C" void kernel_launch(void* const* d_in, const int* in_sizes, int n_in,
                              void* d_out, int out_size, void* d_ws, size_t ws_size,
                              hipStream_t stream)
{
    const float* th   = (const float*)d_in[0];
    const float* phis = (const float*)d_in[1];
    float* out = (float*)d_out;
    const int B = in_sizes[0];             // 2097152 thetas
    const int block = 256;
    const int grid = (B + block - 1) / block;
    qsp_kernel<<<grid, block, 0, stream>>>(th, phis, out, B);
}

// Round 2
// 132.930 us; speedup vs baseline: 1.5261x; 1.5261x over previous
//
#include <hip/hip_runtime.h>

// QSP: u = Rz(phi0) * prod_{k=1..127} [ Wx(theta) * Rz(phi_k) ],  SU(2) state (a,b).
//   t_a = a*c + i*b*s ; t_b = i*a*s + b*c ; a = t_a*e_k ; b = t_b*conj(e_k)
// R1: 2 elements/thread via packed fp32 (v_pk_fma_f32), phase table pre-splatted
// in LDS as {c,c,s,s} so ds_read_b128 delivers ready splat pairs.

typedef float v2f __attribute__((ext_vector_type(2)));

#define NPHI 128

__global__ __launch_bounds__(256) void qsp_kernel(
    const float* __restrict__ th,
    const float* __restrict__ phis,
    float* __restrict__ out,   // [0,B): real, [B,2B): imag
    int Bhalf)                 // B/2 (elements per thread = 2)
{
    __shared__ float4 tab[NPHI];  // {cos phi, cos phi, sin phi, sin phi}
    const int tid = threadIdx.x;
    if (tid < NPHI) {
        float sp, cp;
        __sincosf(phis[tid], &sp, &cp);
        tab[tid] = make_float4(cp, cp, sp, sp);
    }
    __syncthreads();

    const int g = blockIdx.x * blockDim.x + tid;
    if (g >= Bhalf) return;

    // two consecutive thetas, 8B coalesced load
    const float2 t2 = ((const float2*)th)[g];
    float s0, c0, s1, c1;
    __sincosf(t2.x, &s0, &c0);
    __sincosf(t2.y, &s1, &c1);
    const v2f c = {c0, c1};
    const v2f s = {s0, s1};

    // u0 = Rz(phi0): a = e0, b = 0 (same for both packed elements)
    const float4 e0 = tab[0];
    v2f ar = {e0.x, e0.x}, ai = {e0.z, e0.z};
    v2f br = {0.f, 0.f},  bi = {0.f, 0.f};

    #pragma unroll 8
    for (int k = 1; k < NPHI; ++k) {
        const float4 ek = tab[k];       // ds_read_b128, broadcast
        const v2f ex = {ek.x, ek.y};    // splat pair: cos phi_k
        const v2f ey = {ek.z, ek.w};    // splat pair: sin phi_k
        // Wx apply
        const v2f tar = __builtin_elementwise_fma(ar, c, -(bi * s));
        const v2f tai = __builtin_elementwise_fma(ai, c,  (br * s));
        const v2f tbr = __builtin_elementwise_fma(br, c, -(ai * s));
        const v2f tbi = __builtin_elementwise_fma(bi, c,  (ar * s));
        // Rz apply: a = t_a*e_k, b = t_b*conj(e_k)
        ar = __builtin_elementwise_fma(tar, ex, -(tai * ey));
        ai = __builtin_elementwise_fma(tar, ey,  (tai * ex));
        br = __builtin_elementwise_fma(tbr, ex,  (tbi * ey));
        bi = __builtin_elementwise_fma(tbi, ex, -(tbr * ey));
    }

    // real parts of elements 2g,2g+1 ; imag at +B
    ((float2*)out)[g]         = make_float2(ar.x, ar.y);
    ((float2*)out)[g + Bhalf] = make_float2(ai.x, ai.y);
}

extern "C" void kernel_launch(void* const* d_in, const int* in_sizes, int n_in,
                              void* d_out, int out_size, void* d_ws, size_t ws_size,
                              hipStream_t stream)
{
    const float* th   = (const float*)d_in[0];
    const float* phis = (const float*)d_in[1];
    float* out = (float*)d_out;
    const int B = in_sizes[0];          // 2097152
    const int Bhalf = B >> 1;
    const int block = 256;
    const int grid = (Bhalf + block - 1) / block;
    qsp_kernel<<<grid, block, 0, stream>>>(th, phis, out, Bhalf);
}

// Round 3
// 111.101 us; speedup vs baseline: 1.8259x; 1.1965x over previous
//
#include <hip/hip_runtime.h>

// QSP via Laurent polynomial: u00(theta) = sum_{m odd, |m|<=127} gamma_m e^{i m theta}
// Coefficients gamma depend only on phis -> computed once by a tiny setup kernel.
// Main kernel: Horner in z = e^{2 i theta} (128 terms), final rotate by e^{-127 i theta}.
//
// Coefficient recurrence (row (A,B) of U, power-indexed arrays, w = e^{i theta},
// c = (w+w^-1)/2, i s = (w-w^-1)/2):
//   A'[m] = e_k * (A[m-1] + A[m+1] + B[m-1] - B[m+1]) / 2
//   B'[m] = conj(e_k) * (A[m-1] - A[m+1] + B[m-1] + B[m+1]) / 2
// Init: A[0] = e_0, B = 0.  After 127 steps, gamma_j = A[2j-127], j=0..127.

typedef float v2f __attribute__((ext_vector_type(2)));

#define NPHI 128
#define NCOEF 255          // powers -127..127, idx = m+127
#define NPAD  (NCOEF + 2)  // guard zeros at both ends, physical p = idx+1

__global__ __launch_bounds__(256) void qsp_setup(
    const float* __restrict__ phis,
    float4* __restrict__ tab)       // 128 entries: {gr, gr, gi, gi}
{
    __shared__ float2 e[NPHI];
    __shared__ float2 Abuf[2][NPAD];
    __shared__ float2 Bbuf[2][NPAD];
    const int t = threadIdx.x;

    if (t < NPHI) {
        float sp, cp;
        __sincosf(phis[t], &sp, &cp);
        e[t] = make_float2(cp, sp);
    }
    // zero both buffers (guards included)
    if (t < NPAD) {
        Abuf[0][t] = make_float2(0.f, 0.f);
        Abuf[1][t] = make_float2(0.f, 0.f);
        Bbuf[0][t] = make_float2(0.f, 0.f);
        Bbuf[1][t] = make_float2(0.f, 0.f);
    }
    if (t == 0) {  // NPAD = 257 > 256: last slot
        Abuf[0][NPAD - 1] = make_float2(0.f, 0.f);
        Abuf[1][NPAD - 1] = make_float2(0.f, 0.f);
        Bbuf[0][NPAD - 1] = make_float2(0.f, 0.f);
        Bbuf[1][NPAD - 1] = make_float2(0.f, 0.f);
    }
    __syncthreads();
    if (t == 0) Abuf[0][128] = e[0];   // power 0 -> idx 127 -> p 128
    __syncthreads();

    int cur = 0;
    for (int k = 1; k < NPHI; ++k) {
        if (t < NCOEF) {
            const int p = t + 1;
            const float2 Am = Abuf[cur][p - 1], Ap = Abuf[cur][p + 1];
            const float2 Bm = Bbuf[cur][p - 1], Bp = Bbuf[cur][p + 1];
            const float sAr = 0.5f * (Am.x + Ap.x + Bm.x - Bp.x);
            const float sAi = 0.5f * (Am.y + Ap.y + Bm.y - Bp.y);
            const float sBr = 0.5f * (Am.x - Ap.x + Bm.x + Bp.x);
            const float sBi = 0.5f * (Am.y - Ap.y + Bm.y + Bp.y);
            const float2 ek = e[k];
            Abuf[1 - cur][p] = make_float2(ek.x * sAr - ek.y * sAi,
                                           ek.x * sAi + ek.y * sAr);
            Bbuf[1 - cur][p] = make_float2(ek.x * sBr + ek.y * sBi,
                                           ek.x * sBi - ek.y * sBr);
        }
        cur = 1 - cur;
        __syncthreads();
    }

    if (t < NPHI) {
        // gamma_t = A[power 2t-127] -> idx 2t -> p 2t+1
        const float2 g = Abuf[cur][2 * t + 1];
        tab[t] = make_float4(g.x, g.x, g.y, g.y);
    }
}

__global__ __launch_bounds__(256) void qsp_main(
    const float* __restrict__ th,
    const float4* __restrict__ tab,
    float* __restrict__ out,    // [0,B): real, [B,2B): imag
    int Bhalf)
{
    __shared__ float4 g[NPHI];
    const int tid = threadIdx.x;
    if (tid < NPHI) g[tid] = tab[tid];
    __syncthreads();

    const int idx = blockIdx.x * blockDim.x + tid;
    if (idx >= Bhalf) return;

    const float2 t2 = ((const float2*)th)[idx];

    // z = e^{2 i theta} for both packed elements
    float zs0, zc0, zs1, zc1;
    __sincosf(2.f * t2.x, &zs0, &zc0);
    __sincosf(2.f * t2.y, &zs1, &zc1);
    const v2f zr = {zc0, zc1};
    const v2f zi = {zs0, zs1};
    const v2f nzi = {-zs0, -zs1};

    // Horner: acc = gamma_127; acc = acc*z + gamma_j
    const float4 gt = g[NPHI - 1];
    v2f ar = {gt.x, gt.y};
    v2f ai = {gt.z, gt.w};

    #pragma unroll 8
    for (int j = NPHI - 2; j >= 0; --j) {
        const float4 gj = g[j];   // ds_read_b128, broadcast
        const v2f nr = __builtin_elementwise_fma(
            ar, zr, __builtin_elementwise_fma(ai, nzi, (v2f){gj.x, gj.y}));
        const v2f ni = __builtin_elementwise_fma(
            ar, zi, __builtin_elementwise_fma(ai, zr, (v2f){gj.z, gj.w}));
        ar = nr; ai = ni;
    }

    // multiply by e^{-127 i theta}: real = ar*C + ai*S ; imag = ai*C - ar*S
    float S0, C0, S1, C1;
    __sincosf(127.f * t2.x, &S0, &C0);
    __sincosf(127.f * t2.y, &S1, &C1);
    const v2f C = {C0, C1};
    const v2f S = {S0, S1};
    const v2f outr = __builtin_elementwise_fma(ar, C, ai * S);
    const v2f outi = __builtin_elementwise_fma(ai, C, -(ar * S));

    ((float2*)out)[idx]         = make_float2(outr.x, outr.y);
    ((float2*)out)[idx + Bhalf] = make_float2(outi.x, outi.y);
}

extern "C" void kernel_launch(void* const* d_in, const int* in_sizes, int n_in,
                              void* d_out, int out_size, void* d_ws, size_t ws_size,
                              hipStream_t stream)
{
    const float* th   = (const float*)d_in[0];
    const float* phis = (const float*)d_in[1];
    float* out = (float*)d_out;
    float4* tab = (float4*)d_ws;        // 128 * 16 B = 2 KB scratch
    const int B = in_sizes[0];          // 2097152
    const int Bhalf = B >> 1;

    qsp_setup<<<1, 256, 0, stream>>>(phis, tab);

    const int block = 256;
    const int grid = (Bhalf + block - 1) / block;
    qsp_main<<<grid, block, 0, stream>>>(th, tab, out, Bhalf);
}

// Round 4
// 109.147 us; speedup vs baseline: 1.8586x; 1.0179x over previous
//
#include <hip/hip_runtime.h>

// QSP via Laurent polynomial: u00(theta) = sum_{m odd, |m|<=127} gamma_m e^{i m theta}
// Setup kernel (1 block): coefficient recurrence over phis -> 128 complex gammas,
// written splatted {gr,gr,gi,gi} to d_ws.
// Main kernel: Horner in z = e^{2 i theta}, coefficients via UNIFORM scalar loads
// (s_load -> SGPR pairs feed v_pk_fma_f32 directly; no LDS). 4 elements/thread.

typedef float v2f __attribute__((ext_vector_type(2)));

#define NPHI 128
#define NCOEF 255          // powers -127..127, idx = m+127
#define NPAD  (NCOEF + 2)  // guard zeros at both ends, physical p = idx+1

__global__ __launch_bounds__(256) void qsp_setup(
    const float* __restrict__ phis,
    float4* __restrict__ tab)       // 128 entries: {gr, gr, gi, gi}
{
    __shared__ float2 e[NPHI];
    __shared__ float2 Abuf[2][NPAD];
    __shared__ float2 Bbuf[2][NPAD];
    const int t = threadIdx.x;

    if (t < NPHI) {
        float sp, cp;
        __sincosf(phis[t], &sp, &cp);
        e[t] = make_float2(cp, sp);
    }
    if (t < NPAD) {
        Abuf[0][t] = make_float2(0.f, 0.f);
        Abuf[1][t] = make_float2(0.f, 0.f);
        Bbuf[0][t] = make_float2(0.f, 0.f);
        Bbuf[1][t] = make_float2(0.f, 0.f);
    }
    if (t == 0) {  // NPAD = 257 > 256
        Abuf[0][NPAD - 1] = make_float2(0.f, 0.f);
        Abuf[1][NPAD - 1] = make_float2(0.f, 0.f);
        Bbuf[0][NPAD - 1] = make_float2(0.f, 0.f);
        Bbuf[1][NPAD - 1] = make_float2(0.f, 0.f);
    }
    __syncthreads();
    if (t == 0) Abuf[0][128] = e[0];   // power 0 -> idx 127 -> p 128
    __syncthreads();

    int cur = 0;
    for (int k = 1; k < NPHI; ++k) {
        if (t < NCOEF) {
            const int p = t + 1;
            const float2 Am = Abuf[cur][p - 1], Ap = Abuf[cur][p + 1];
            const float2 Bm = Bbuf[cur][p - 1], Bp = Bbuf[cur][p + 1];
            const float sAr = 0.5f * (Am.x + Ap.x + Bm.x - Bp.x);
            const float sAi = 0.5f * (Am.y + Ap.y + Bm.y - Bp.y);
            const float sBr = 0.5f * (Am.x - Ap.x + Bm.x + Bp.x);
            const float sBi = 0.5f * (Am.y - Ap.y + Bm.y + Bp.y);
            const float2 ek = e[k];
            Abuf[1 - cur][p] = make_float2(ek.x * sAr - ek.y * sAi,
                                           ek.x * sAi + ek.y * sAr);
            Bbuf[1 - cur][p] = make_float2(ek.x * sBr + ek.y * sBi,
                                           ek.x * sBi - ek.y * sBr);
        }
        cur = 1 - cur;
        __syncthreads();
    }

    if (t < NPHI) {
        const float2 g = Abuf[cur][2 * t + 1];   // gamma_t
        tab[t] = make_float4(g.x, g.x, g.y, g.y);
    }
}

__global__ __launch_bounds__(256) void qsp_main(
    const float* __restrict__ th,
    const float4* __restrict__ tab,   // uniform scalar loads
    float* __restrict__ out,          // [0,B): real, [B,2B): imag
    int Bq)                            // B/4
{
    const int idx = blockIdx.x * blockDim.x + threadIdx.x;
    if (idx >= Bq) return;

    const float4 t4 = ((const float4*)th)[idx];   // 4 thetas, 16B coalesced

    // z = e^{2 i theta}
    float zs0, zc0, zs1, zc1, zs2, zc2, zs3, zc3;
    __sincosf(2.f * t4.x, &zs0, &zc0);
    __sincosf(2.f * t4.y, &zs1, &zc1);
    __sincosf(2.f * t4.z, &zs2, &zc2);
    __sincosf(2.f * t4.w, &zs3, &zc3);
    const v2f zrA = {zc0, zc1}, ziA = {zs0, zs1}, nziA = {-zs0, -zs1};
    const v2f zrB = {zc2, zc3}, ziB = {zs2, zs3}, nziB = {-zs2, -zs3};

    // Horner init: acc = gamma_127
    const float4 gt = tab[NPHI - 1];
    v2f arA = {gt.x, gt.y}, aiA = {gt.z, gt.w};
    v2f arB = {gt.x, gt.y}, aiB = {gt.z, gt.w};

    #pragma unroll 8
    for (int j = NPHI - 2; j >= 0; --j) {
        const float4 gj = tab[j];                 // s_load_dwordx4 (uniform)
        const v2f gr = {gj.x, gj.y};              // SGPR pair {gr,gr}
        const v2f gi = {gj.z, gj.w};              // SGPR pair {gi,gi}
        const v2f nrA = __builtin_elementwise_fma(
            arA, zrA, __builtin_elementwise_fma(aiA, nziA, gr));
        const v2f niA = __builtin_elementwise_fma(
            arA, ziA, __builtin_elementwise_fma(aiA, zrA, gi));
        const v2f nrB = __builtin_elementwise_fma(
            arB, zrB, __builtin_elementwise_fma(aiB, nziB, gr));
        const v2f niB = __builtin_elementwise_fma(
            arB, ziB, __builtin_elementwise_fma(aiB, zrB, gi));
        arA = nrA; aiA = niA;
        arB = nrB; aiB = niB;
    }

    // multiply by e^{-127 i theta}
    float S0, C0, S1, C1, S2, C2, S3, C3;
    __sincosf(127.f * t4.x, &S0, &C0);
    __sincosf(127.f * t4.y, &S1, &C1);
    __sincosf(127.f * t4.z, &S2, &C2);
    __sincosf(127.f * t4.w, &S3, &C3);
    const v2f CA = {C0, C1}, SA = {S0, S1};
    const v2f CB = {C2, C3}, SB = {S2, S3};
    const v2f orA = __builtin_elementwise_fma(arA, CA, aiA * SA);
    const v2f oiA = __builtin_elementwise_fma(aiA, CA, -(arA * SA));
    const v2f orB = __builtin_elementwise_fma(arB, CB, aiB * SB);
    const v2f oiB = __builtin_elementwise_fma(aiB, CB, -(arB * SB));

    ((float4*)out)[idx]      = make_float4(orA.x, orA.y, orB.x, orB.y);
    ((float4*)out)[idx + Bq] = make_float4(oiA.x, oiA.y, oiB.x, oiB.y);
}

extern "C" void kernel_launch(void* const* d_in, const int* in_sizes, int n_in,
                              void* d_out, int out_size, void* d_ws, size_t ws_size,
                              hipStream_t stream)
{
    const float* th   = (const float*)d_in[0];
    const float* phis = (const float*)d_in[1];
    float* out = (float*)d_out;
    float4* tab = (float4*)d_ws;        // 128 * 16 B = 2 KB scratch
    const int B = in_sizes[0];          // 2097152
    const int Bq = B >> 2;

    qsp_setup<<<1, 256, 0, stream>>>(phis, tab);

    const int block = 256;
    const int grid = (Bq + block - 1) / block;
    qsp_main<<<grid, block, 0, stream>>>(th, tab, out, Bq);
}